// Round 9
// baseline (212.128 us; speedup 1.0000x reference)
//
#include <hip/hip_runtime.h>
#include <hip/hip_bf16.h>
#include <cstdint>
#include <cstddef>

#define BATCH   2048
#define DIM     1024   // D == H == 1024
#define NSTEPS  2      // RK3 steps; h = 1/NSTEPS  (12 GEMM phases)

typedef __attribute__((ext_vector_type(8))) short short8;
typedef __attribute__((ext_vector_type(4))) float f32x4;
typedef _Float16 half8 __attribute__((ext_vector_type(8)));

static __device__ __forceinline__ unsigned short f2h(float x) {
    _Float16 h = (_Float16)x;
    return __builtin_bit_cast(unsigned short, h);
}
static __device__ __forceinline__ float h2f(unsigned short u) {
    return (float)__builtin_bit_cast(_Float16, u);
}
static __device__ __forceinline__ float tanh_fast(float x) {
    // exact at saturation: e=inf -> 1 ; e=0 -> -1. rel err ~2e-6.
    float e = __expf(2.0f * x);
    return 1.0f - 2.0f / (e + 1.0f);
}

struct PArgs {
    const float* z0; const float* W1; const float* b1;
    const float* W2; const float* b2;
    float* zbuf;                          // d_out: fp32 state
    unsigned short* W1T; unsigned short* W2T;   // f16 [N][K]
    unsigned short* zin; unsigned short* hid;   // f16 activations
    unsigned short* accb;                       // f16 RK accumulator
    unsigned int* ctr;   // [0]=dev barrier, [1..8]=slot per XCD, [9..16]=xbar per XCD
};

// ---------------------------------------------------------------------------
// ONE persistent cooperative kernel. XCD-local row ownership:
//   physical XCD x (s_getreg XCC_ID) owns rows [x*256, x*256+256): bm = 2x+..
//   All activation traffic (zin/hid/accb/zbuf) stays within one L2.
//   Phase barriers are XCD-local: vmcnt(0) + per-XCD atomic counter. NO
//   threadfence / L2 writeback (R4's failure mode). Weights cross XCDs once:
//   prep stores W^T with system-scope (through L2 to memory-side L3), one
//   device-wide counter barrier, then read-only.
//   Staging loads use aux=SC0 (bypass L1) since zin/hid are rewritten by
//   other CUs of the same XCD each phase; CDNA L1 is write-through so
//   vmcnt(0) before the barrier makes stores L2-visible.
// Per phase: R8's verified GEMM (tile 128x64, 8 waves, partial-K waves,
// triple-buffered counted-vmcnt staging pipeline, LDS exchange epilogue).
// ---------------------------------------------------------------------------
__global__ __launch_bounds__(512) void ode_persist(PArgs a) {
    constexpr float hstep = 1.0f / NSTEPS;
    __shared__ char smem_raw[147456];            // 144 KB -> 1 block/CU
    short8* stg = (short8*)smem_raw;             // 3 bufs x 3072 slots
    float*  xch = (float*)smem_raw;              // 8 regions x 4224 f32

    const int tid  = threadIdx.x;
    const int wave = tid >> 6;
    const int lane = tid & 63;
    const int l15 = lane & 15, lhi = lane >> 4;
    const int wp   = wave & 1;
    const int rsub = (wave >> 1) & 1;
    const int kh   = wave >> 2;

    // ---- physical XCD + slot grab (coop launch + 1 blk/CU => exactly 32/XCD)
    unsigned int xcc;
    asm volatile("s_getreg_b32 %0, hwreg(HW_REG_XCC_ID)" : "=s"(xcc));
    xcc &= 7u;
    __shared__ int s_slot;
    if (tid == 0) s_slot = (int)atomicAdd(&a.ctr[1 + xcc], 1u);
    __syncthreads();
    const int slot = s_slot & 31;
    const int bm = (int)xcc * 2 + (slot >> 4);   // rows [bm*128, +128)
    const int bn = slot & 15;                    // cols [bn*64, +64)

    // ---------------- prep ----------------
    {   // z init: rows [bm*128 + bn*8, +8)  (XCD-local consumers only)
        const int r0 = bm * 128 + bn * 8;
        const float4* z4  = (const float4*)a.z0 + (size_t)r0 * (DIM / 4);
        float4*       zb4 = (float4*)a.zbuf     + (size_t)r0 * (DIM / 4);
        ushort4*      zi4 = (ushort4*)a.zin     + (size_t)r0 * (DIM / 4);
#pragma unroll
        for (int r = 0; r < 4; ++r) {
            const int i = r * 512 + tid;         // 8 rows x 256 float4
            float4 v = z4[i];
            zb4[i] = v;
            ushort4 q;
            q.x = f2h(v.x); q.y = f2h(v.y); q.z = f2h(v.z); q.w = f2h(v.w);
            zi4[i] = q;
        }
    }
    {   // W transpose: 2 tiles per block; stores system-scope (cross-XCD via L3)
        unsigned short (*tile)[65] = (unsigned short (*)[65])smem_raw;
        const int base = ((int)xcc * 32 + slot) * 2;
        for (int tt = 0; tt < 2; ++tt) {
            const int tbid = base + tt;
            const float* in = (tbid < 256) ? a.W1 : a.W2;
            unsigned short* out = (tbid < 256) ? a.W1T : a.W2T;
            const int tb = tbid & 255;
            const int nb = (tb & 15) * 64, kb = (tb >> 4) * 64;
            const int cx = tid & 63, ry = tid >> 6;   // 64 x 8
            __syncthreads();
#pragma unroll
            for (int r = 0; r < 8; ++r) {
                const int k = r * 8 + ry;
                tile[cx][k] = f2h(in[(size_t)(kb + k) * DIM + (nb + cx)]);
            }
            __syncthreads();
            const int cx2 = tid & 31, ry2 = tid >> 5; // 32 x 16, packed u32 writes
#pragma unroll
            for (int r = 0; r < 4; ++r) {
                const int n = r * 16 + ry2;
                unsigned int val = (unsigned)tile[n][cx2 * 2]
                                 | ((unsigned)tile[n][cx2 * 2 + 1] << 16);
                __hip_atomic_store(
                    (unsigned int*)&out[(size_t)(nb + n) * DIM + kb] + cx2, val,
                    __ATOMIC_RELAXED, __HIP_MEMORY_SCOPE_SYSTEM);
            }
        }
    }
    // ---- one-time device-wide barrier (weights become read-only after) ----
    asm volatile("s_waitcnt vmcnt(0)" ::: "memory");
    __syncthreads();
    if (tid == 0) {
        atomicAdd(&a.ctr[0], 1u);
        long spin = 0;
        while (__hip_atomic_load(&a.ctr[0], __ATOMIC_RELAXED, __HIP_MEMORY_SCOPE_AGENT) < 256u) {
            __builtin_amdgcn_s_sleep(2);
            if (++spin > (1L << 22)) break;   // bounded: never hang
        }
    }
    __syncthreads();

    // ---- staging offsets (A geometry identical for zin/hid) ----
    int offA[4], offB[2];
#pragma unroll
    for (int c = 0; c < 4; ++c) {
        const int g = c * 512 + tid;
        const int half = g >> 10, s = g & 1023;
        const int row = s >> 3, k16 = (s & 7) ^ (row & 7);
        offA[c] = (bm * 128 + row) * DIM + half * 512 + k16 * 8;
    }
#pragma unroll
    for (int c = 0; c < 2; ++c) {
        const int g = c * 512 + tid;
        const int half = g >> 9, s = g & 511;
        const int row = s >> 3, k16 = (s & 7) ^ (row & 7);
        offB[c] = (bn * 64 + row) * DIM + half * 512 + k16 * 8;
    }

    // ---------------- 12 GEMM phases ----------------
    unsigned int epoch = 0;
    for (int ph = 0; ph < 12; ++ph) {
        const int sub = ph % 6;
        const bool g1 = (sub & 1) == 0;
        const int mode = g1 ? 0 : (sub >> 1) + 1;      // 0 | 1,2,3
        const unsigned short* A  = g1 ? a.zin : a.hid;
        const unsigned short* Bw = g1 ? a.W1T : a.W2T;
        const float* bias        = g1 ? a.b1  : a.b2;

        f32x4 acc[4][4] = {};

        auto stage = [&](int sbuf, int t) {
#pragma unroll
            for (int c = 0; c < 4; ++c)
                __builtin_amdgcn_global_load_lds(
                    (const __attribute__((address_space(1))) void*)(A + offA[c] + t * 64),
                    (__attribute__((address_space(3))) void*)&stg[sbuf * 3072 + c * 512 + (wave << 6)],
                    16, 0, 1 /* SC0: bypass L1 (rewritten by same-XCD CUs) */);
#pragma unroll
            for (int c = 0; c < 2; ++c)
                __builtin_amdgcn_global_load_lds(
                    (const __attribute__((address_space(1))) void*)(Bw + offB[c] + t * 64),
                    (__attribute__((address_space(3))) void*)&stg[sbuf * 3072 + 2048 + c * 512 + (wave << 6)],
                    16, 0, 1);
        };

        stage(0, 0);
        stage(1, 1);  // 12 loads in flight

        for (int t = 0; t < 8; ++t) {
            if (t < 7) asm volatile("s_waitcnt vmcnt(6)" ::: "memory");
            else       asm volatile("s_waitcnt vmcnt(0)" ::: "memory");
            __builtin_amdgcn_s_barrier();
            __builtin_amdgcn_sched_barrier(0);

            if (t + 2 < 8) stage((t + 2) % 3, t + 2);

            const char* sa = (const char*)&stg[(t % 3) * 3072 + kh * 1024];
            const char* sb = (const char*)&stg[(t % 3) * 3072 + 2048 + kh * 512];
            half8 af[4], bq[4];
#pragma unroll
            for (int m = 0; m < 4; ++m) {
                const int row  = rsub * 64 + m * 16 + l15;
                const int byte = row * 128 + ((wp * 64 + lhi * 16) ^ ((row & 7) << 4));
                af[m] = *(const half8*)(sa + byte);
            }
#pragma unroll
            for (int n = 0; n < 4; ++n) {
                const int row  = n * 16 + l15;
                const int byte = row * 128 + ((wp * 64 + lhi * 16) ^ ((row & 7) << 4));
                bq[n] = *(const half8*)(sb + byte);
            }
            __builtin_amdgcn_s_setprio(1);
#pragma unroll
            for (int m = 0; m < 4; ++m)
#pragma unroll
                for (int n = 0; n < 4; ++n)
                    acc[m][n] = __builtin_amdgcn_mfma_f32_16x16x32_f16(af[m], bq[n], acc[m][n], 0, 0, 0);
            __builtin_amdgcn_s_setprio(0);
        }

        __syncthreads();  // staging LDS quiesced before exchange overwrites it

        {   // all 8 waves write partials
            const int cidx = kh * 2 + wp;
            const int rbase = (rsub * 4 + cidx) * 4224;
#pragma unroll
            for (int m = 0; m < 4; ++m)
#pragma unroll
                for (int n = 0; n < 4; ++n)
#pragma unroll
                    for (int r = 0; r < 4; ++r)
                        xch[rbase + (m * 4 + n) * 264 + r * 64 + lane] = acc[m][n][r];
        }
        __syncthreads();

        {   // all 512 threads: one row x 16 contiguous cols
            const int row  = tid >> 2;
            const int rsb  = row >> 6;
            const int r64  = row & 63;
            const int m    = r64 >> 4;
            const int lh   = (r64 & 15) >> 2;
            const int rr   = r64 & 3;
            const int n    = tid & 3;
            const int ebase = (m * 4 + n) * 264 + rr * 64 + lh * 16;

            f32x4 sum[4] = {};
#pragma unroll
            for (int c = 0; c < 4; ++c) {
                const float* p = xch + (rsb * 4 + c) * 4224 + ebase;
#pragma unroll
                for (int q = 0; q < 4; ++q)
                    sum[q] += *(const f32x4*)(p + 4 * q);
            }

            const int grow = bm * 128 + row;
            const int gcol = bn * 64 + n * 16;
            const size_t gidx = (size_t)grow * DIM + gcol;

            unsigned short hh[16];   // zin or hid (f16)
            unsigned short aa[16];   // accb (f16), modes 1,2
#pragma unroll
            for (int q = 0; q < 4; ++q) {
                f32x4 v = sum[q] + *(const f32x4*)&bias[gcol + 4 * q];
                if (mode == 0) {
#pragma unroll
                    for (int j = 0; j < 4; ++j) hh[q * 4 + j] = f2h(tanh_fast(v[j]));
                } else if (mode == 1) {        // k1
                    f32x4 z = *(const f32x4*)&a.zbuf[gidx + 4 * q];
#pragma unroll
                    for (int j = 0; j < 4; ++j) {
                        aa[q * 4 + j] = f2h(v[j]);
                        hh[q * 4 + j] = f2h(z[j] + (0.5f * hstep) * v[j]);
                    }
                } else if (mode == 2) {        // k2
                    const short8 a0l = *(const short8*)&a.accb[gidx + 4 * (q & ~1)]; // 8 halves
                    f32x4 z = *(const f32x4*)&a.zbuf[gidx + 4 * q];
#pragma unroll
                    for (int j = 0; j < 4; ++j) {
                        const float k1 = h2f(((const unsigned short*)&a0l)[(q & 1) * 4 + j]);
                        hh[q * 4 + j] = f2h(z[j] + hstep * (2.0f * v[j] - k1));
                        aa[q * 4 + j] = f2h(k1 + 4.0f * v[j]);
                    }
                } else {                       // mode 3: finalize
                    const short8 a0l = *(const short8*)&a.accb[gidx + 4 * (q & ~1)];
                    f32x4 z = *(const f32x4*)&a.zbuf[gidx + 4 * q];
                    f32x4 zn;
#pragma unroll
                    for (int j = 0; j < 4; ++j) {
                        const float s0 = h2f(((const unsigned short*)&a0l)[(q & 1) * 4 + j]);
                        zn[j] = z[j] + (hstep / 6.0f) * (s0 + v[j]);
                        hh[q * 4 + j] = f2h(zn[j]);
                    }
                    *(f32x4*)&a.zbuf[gidx + 4 * q] = zn;
                }
            }
            short8 s0, s1;
#pragma unroll
            for (int j = 0; j < 8; ++j) { s0[j] = (short)hh[j]; s1[j] = (short)hh[j + 8]; }
            if (mode == 0) {
                *(short8*)&a.hid[gidx] = s0;  *(short8*)&a.hid[gidx + 8] = s1;
            } else {
                *(short8*)&a.zin[gidx] = s0;  *(short8*)&a.zin[gidx + 8] = s1;
                if (mode == 1 || mode == 2) {
                    short8 a0, a1;
#pragma unroll
                    for (int j = 0; j < 8; ++j) { a0[j] = (short)aa[j]; a1[j] = (short)aa[j + 8]; }
                    *(short8*)&a.accb[gidx] = a0;  *(short8*)&a.accb[gidx + 8] = a1;
                }
            }
        }

        if (ph < 11) {  // XCD-local barrier: vmcnt drain + per-XCD counter. No L2 flush.
            asm volatile("s_waitcnt vmcnt(0)" ::: "memory");
            __syncthreads();
            ++epoch;
            if (tid == 0) {
                atomicAdd(&a.ctr[9 + xcc], 1u);
                const unsigned int target = 32u * epoch;
                long spin = 0;
                while (__hip_atomic_load(&a.ctr[9 + xcc], __ATOMIC_RELAXED, __HIP_MEMORY_SCOPE_AGENT) < target) {
                    __builtin_amdgcn_s_sleep(2);
                    if (++spin > (1L << 22)) break;
                }
            }
            __syncthreads();
        }
    }
}

// ---------------------------------------------------------------------------
extern "C" void kernel_launch(void* const* d_in, const int* in_sizes, int n_in,
                              void* d_out, int out_size, void* d_ws, size_t ws_size,
                              hipStream_t stream) {
    (void)in_sizes; (void)n_in; (void)out_size; (void)ws_size;
    char* ws = (char*)d_ws;

    PArgs args;
    args.z0   = (const float*)d_in[0];
    args.W1   = (const float*)d_in[1];
    args.b1   = (const float*)d_in[2];
    args.W2   = (const float*)d_in[3];
    args.b2   = (const float*)d_in[4];
    args.zbuf = (float*)d_out;
    args.W1T  = (unsigned short*)(ws);                 // 2 MB f16 [H][D]
    args.W2T  = (unsigned short*)(ws + (2u  << 20));   // 2 MB f16 [D][H]
    args.zin  = (unsigned short*)(ws + (4u  << 20));   // 4 MB f16
    args.hid  = (unsigned short*)(ws + (8u  << 20));   // 4 MB f16
    args.accb = (unsigned short*)(ws + (12u << 20));   // 4 MB f16
    args.ctr  = (unsigned int*)  (ws + (16u << 20));   // barrier/slot counters

    hipMemsetAsync(args.ctr, 0, 256, stream);          // zero every call (graph node)

    void* kargs[] = { &args };
    hipError_t e = hipLaunchCooperativeKernel((const void*)ode_persist,
                                              dim3(256), dim3(512),
                                              kargs, 0, stream);
    if (e != hipSuccess) {
        // Fallback: 144 KB LDS forces 1 block/CU; 256 blocks on 256 CUs still
        // co-resident on a healthy part.
        ode_persist<<<dim3(256), dim3(512), 0, stream>>>(args);
    }
}

// Round 10
// 158.926 us; speedup vs baseline: 1.3348x; 1.3348x over previous
//
#include <hip/hip_runtime.h>
#include <hip/hip_bf16.h>
#include <cstdint>
#include <cstddef>

#define BATCH   2048
#define DIM     1024   // D == H == 1024
#define NSTEPS  2      // RK3 steps; h = 1/NSTEPS

typedef __attribute__((ext_vector_type(8))) short short8;
typedef __attribute__((ext_vector_type(4))) float f32x4;
typedef _Float16 half8 __attribute__((ext_vector_type(8)));

static __device__ __forceinline__ unsigned short f2h(float x) {
    _Float16 h = (_Float16)x;                    // v_cvt_f16_f32 (RTN)
    return __builtin_bit_cast(unsigned short, h);
}

// ---------------------------------------------------------------------------
// Fused prep (ONE dispatch): z/zin init (all 2048 blocks) + W1/W2 transpose
// to f16 [N][K] (blocks 0..511, one 64x64 tile each).
// ---------------------------------------------------------------------------
__global__ __launch_bounds__(256) void prep_all(const float* __restrict__ W1,
                                                const float* __restrict__ W2,
                                                const float* __restrict__ z0,
                                                float* __restrict__ z,
                                                unsigned short* __restrict__ W1T,
                                                unsigned short* __restrict__ W2T,
                                                unsigned short* __restrict__ zin) {
    __shared__ unsigned short tile[64][65];
    const int b = blockIdx.x;

    {   // init: one float4 per thread
        const int i = b * 256 + threadIdx.x;
        float4 v = ((const float4*)z0)[i];
        ((float4*)z)[i] = v;
        ushort4 q;
        q.x = f2h(v.x); q.y = f2h(v.y); q.z = f2h(v.z); q.w = f2h(v.w);
        ((ushort4*)zin)[i] = q;
    }

    if (b < 512) {  // transpose one 64x64 tile of W1 (b<256) or W2
        const float* in = (b < 256) ? W1 : W2;
        unsigned short* out = (b < 256) ? W1T : W2T;
        const int tb = b & 255;
        const int nb = (tb & 15) * 64, kb = (tb >> 4) * 64;
        const int cx = threadIdx.x & 63, ry = threadIdx.x >> 6;
#pragma unroll
        for (int r = 0; r < 16; ++r) {
            int k = r * 4 + ry;
            tile[cx][k] = f2h(in[(size_t)(kb + k) * DIM + (nb + cx)]);
        }
        __syncthreads();
#pragma unroll
        for (int r = 0; r < 16; ++r) {
            int n = r * 4 + ry;
            out[(size_t)(nb + n) * DIM + (kb + cx)] = tile[n][cx];
        }
    }
}

// ---------------------------------------------------------------------------
// GEMM: C[m][n] = sum_k A[m][k] * Bw[n][k]  (+ fused epilogue), f16 inputs.
//
// Block tile 128x64, 8 waves (2/SIMD). Wave = (wp = kk parity, rsub = row
// half, kh = K half); partial 64x64 per wave (4x4 frags of 16x16x32 f16).
// Triple-buffered LDS + counted-vmcnt pipeline (T3/T4). XCD swizzle (T1).
//
// Epilogue exchange: XOR-quad swizzled (R9 PMC: 4.78M bank-conflict cycles
// from 16-way reads; swizzle spreads read start-banks to {0,4,..,28} x 8
// lanes = b128 floor). Write phys_col = ((col>>2)^rr)*4 + (col&3); read
// quad (lh*4+q)^rr. Bit-identical numerics.
//
// MODE 0: hid = f16(tanh(C+b))
// MODE 1 (k1): accb = k;           zin = f16(z + (h/2) k)
// MODE 2 (k2): a0 = accb;          zin = f16(z + h (2k - a0)); accb = a0 + 4k
// MODE 3 (k3): z += (h/6)(accb+k); zin = f16(z)
// MODE 4     : like 3 but final step - no zin store
// ---------------------------------------------------------------------------
template<int MODE>
__global__ __launch_bounds__(512) void gemm8w(const unsigned short* __restrict__ A,
                                              const unsigned short* __restrict__ Bw,
                                              const float* __restrict__ bias,
                                              unsigned short* __restrict__ hidOut,
                                              float* __restrict__ zbuf,
                                              float* __restrict__ accb,
                                              unsigned short* __restrict__ zinOut) {
    constexpr float hstep = 1.0f / NSTEPS;
    __shared__ char smem_raw[147456];            // 144 KB (staging ∪ exchange)
    short8* stg = (short8*)smem_raw;             // 3 bufs x 3072 slots
    float*  xch = (float*)smem_raw;              // 8 regions x 4224 f32 = 135 KB

    const int tid  = threadIdx.x;
    const int wave = tid >> 6;
    const int lane = tid & 63;
    const int l15 = lane & 15, lhi = lane >> 4;
    const int wp   = wave & 1;         // kk parity
    const int rsub = (wave >> 1) & 1;  // row half
    const int kh   = wave >> 2;        // K half

    // XCD swizzle: bid%8 = XCD; XCD (ry,rx) owns bm in [ry*4,+4), bn in [rx*8,+8).
    const int bid = blockIdx.x;
    const int xcd = bid & 7, loc = bid >> 3;
    const int bm = (xcd >> 1) * 4 + (loc >> 3);
    const int bn = (xcd & 1) * 8 + (loc & 7);

    f32x4 acc[4][4] = {};

    // Staging: 6 global_load_lds per thread (4 A + 2 B) cover 3072 slots.
    // LDS slot s (linear dest) holds global (row = s>>3, k16 = (s&7)^(row&7)).
    int offA[4], offB[2];
#pragma unroll
    for (int c = 0; c < 4; ++c) {
        const int g = c * 512 + tid;           // [0,2048)
        const int half = g >> 10, s = g & 1023;
        const int row = s >> 3, k16 = (s & 7) ^ (row & 7);
        offA[c] = (bm * 128 + row) * DIM + half * 512 + k16 * 8;
    }
#pragma unroll
    for (int c = 0; c < 2; ++c) {
        const int g = c * 512 + tid;           // [0,1024)
        const int half = g >> 9, s = g & 511;
        const int row = s >> 3, k16 = (s & 7) ^ (row & 7);
        offB[c] = (bn * 64 + row) * DIM + half * 512 + k16 * 8;
    }

    auto stage = [&](int sbuf, int t) {
#pragma unroll
        for (int c = 0; c < 4; ++c)
            __builtin_amdgcn_global_load_lds(
                (const __attribute__((address_space(1))) void*)(A + offA[c] + t * 64),
                (__attribute__((address_space(3))) void*)&stg[sbuf * 3072 + c * 512 + (wave << 6)],
                16, 0, 0);
#pragma unroll
        for (int c = 0; c < 2; ++c)
            __builtin_amdgcn_global_load_lds(
                (const __attribute__((address_space(1))) void*)(Bw + offB[c] + t * 64),
                (__attribute__((address_space(3))) void*)&stg[sbuf * 3072 + 2048 + c * 512 + (wave << 6)],
                16, 0, 0);
    };

    stage(0, 0);
    stage(1, 1);  // 12 loads in flight

    for (int t = 0; t < 8; ++t) {
        if (t < 7) asm volatile("s_waitcnt vmcnt(6)" ::: "memory");
        else       asm volatile("s_waitcnt vmcnt(0)" ::: "memory");
        __builtin_amdgcn_s_barrier();          // raw: no vmcnt(0) drain
        __builtin_amdgcn_sched_barrier(0);     // don't hoist stage above barrier

        if (t + 2 < 8) stage((t + 2) % 3, t + 2);

        const char* sa = (const char*)&stg[(t % 3) * 3072 + kh * 1024];
        const char* sb = (const char*)&stg[(t % 3) * 3072 + 2048 + kh * 512];
        half8 af[4], bq[4];
#pragma unroll
        for (int m = 0; m < 4; ++m) {
            const int row  = rsub * 64 + m * 16 + l15;
            const int byte = row * 128 + ((wp * 64 + lhi * 16) ^ ((row & 7) << 4));
            af[m] = *(const half8*)(sa + byte);
        }
#pragma unroll
        for (int n = 0; n < 4; ++n) {
            const int row  = n * 16 + l15;
            const int byte = row * 128 + ((wp * 64 + lhi * 16) ^ ((row & 7) << 4));
            bq[n] = *(const half8*)(sb + byte);
        }
        __builtin_amdgcn_s_setprio(1);
#pragma unroll
        for (int m = 0; m < 4; ++m)
#pragma unroll
            for (int n = 0; n < 4; ++n)
                acc[m][n] = __builtin_amdgcn_mfma_f32_16x16x32_f16(af[m], bq[n], acc[m][n], 0, 0, 0);
        __builtin_amdgcn_s_setprio(0);
    }

    __syncthreads();  // all waves done with staging LDS before xch overwrites it

    // ---- all 8 waves write partials to the exchange (XOR-quad swizzled) ----
    {
        const int cidx = kh * 2 + wp;
        const int rbase = (rsub * 4 + cidx) * 4224;
        const int q0 = lane >> 2, li = lane & 3;
#pragma unroll
        for (int m = 0; m < 4; ++m)
#pragma unroll
            for (int n = 0; n < 4; ++n)
#pragma unroll
                for (int r = 0; r < 4; ++r)
                    xch[rbase + (m * 4 + n) * 264 + r * 64 + ((q0 ^ r) << 2) + li] = acc[m][n][r];
    }
    __syncthreads();

    // ---- all 512 threads: one row x 16 contiguous (virtual) cols each ----
    {
        const int row  = tid >> 2;           // 0..127
        const int rsb  = row >> 6;
        const int r64  = row & 63;
        const int m    = r64 >> 4;
        const int lh   = (r64 & 15) >> 2;
        const int rr   = r64 & 3;
        const int n    = tid & 3;
        const int fbase = (m * 4 + n) * 264 + rr * 64;

        f32x4 sum[4] = {};
#pragma unroll
        for (int c = 0; c < 4; ++c) {
            const float* p = xch + (rsb * 4 + c) * 4224 + fbase;
#pragma unroll
            for (int q = 0; q < 4; ++q)
                sum[q] += *(const f32x4*)(p + (((lh * 4 + q) ^ rr) << 2));
        }

        const int grow = bm * 128 + row;
        const int gcol = bn * 64 + n * 16;
        const size_t gidx = (size_t)grow * DIM + gcol;

        unsigned short hh[16];
#pragma unroll
        for (int q = 0; q < 4; ++q) {
            f32x4 v = sum[q] + *(const f32x4*)&bias[gcol + 4 * q];
            if (MODE == 0) {
#pragma unroll
                for (int j = 0; j < 4; ++j) hh[q * 4 + j] = f2h(tanhf(v[j]));
            } else if (MODE == 1) {        // k1
                *(f32x4*)&accb[gidx + 4 * q] = v;
                f32x4 z = *(const f32x4*)&zbuf[gidx + 4 * q];
#pragma unroll
                for (int j = 0; j < 4; ++j) hh[q * 4 + j] = f2h(z[j] + (0.5f * hstep) * v[j]);
            } else if (MODE == 2) {        // k2
                f32x4 a0 = *(const f32x4*)&accb[gidx + 4 * q];     // = k1
                f32x4 z  = *(const f32x4*)&zbuf[gidx + 4 * q];
#pragma unroll
                for (int j = 0; j < 4; ++j)
                    hh[q * 4 + j] = f2h(z[j] + hstep * (2.0f * v[j] - a0[j]));
                a0 += 4.0f * v;
                *(f32x4*)&accb[gidx + 4 * q] = a0;                 // k1 + 4 k2
            } else {                       // MODE 3/4: k3, finalize step
                f32x4 a0 = *(const f32x4*)&accb[gidx + 4 * q];
                f32x4 z  = *(const f32x4*)&zbuf[gidx + 4 * q];
                f32x4 zn;
#pragma unroll
                for (int j = 0; j < 4; ++j) zn[j] = z[j] + (hstep / 6.0f) * (a0[j] + v[j]);
                *(f32x4*)&zbuf[gidx + 4 * q] = zn;
                if (MODE == 3) {
#pragma unroll
                    for (int j = 0; j < 4; ++j) hh[q * 4 + j] = f2h(zn[j]);
                }
            }
        }
        if (MODE != 4) {
            short8 s0, s1;
#pragma unroll
            for (int j = 0; j < 8; ++j) { s0[j] = (short)hh[j]; s1[j] = (short)hh[j + 8]; }
            if (MODE == 0) {
                *(short8*)&hidOut[gidx] = s0;  *(short8*)&hidOut[gidx + 8] = s1;
            } else {
                *(short8*)&zinOut[gidx] = s0;  *(short8*)&zinOut[gidx + 8] = s1;
            }
        }
    }
}

// ---------------------------------------------------------------------------
extern "C" void kernel_launch(void* const* d_in, const int* in_sizes, int n_in,
                              void* d_out, int out_size, void* d_ws, size_t ws_size,
                              hipStream_t stream) {
    (void)in_sizes; (void)n_in; (void)out_size; (void)ws_size;
    const float* z0 = (const float*)d_in[0];
    const float* W1 = (const float*)d_in[1];
    const float* b1 = (const float*)d_in[2];
    const float* W2 = (const float*)d_in[3];
    const float* b2 = (const float*)d_in[4];
    float* zbuf = (float*)d_out;  // fp32 state lives in d_out

    char* ws = (char*)d_ws;
    unsigned short* W1T = (unsigned short*)(ws);                 // 2 MB  f16 [H][D]
    unsigned short* W2T = (unsigned short*)(ws + (2u  << 20));   // 2 MB  f16 [D][H]
    unsigned short* zin = (unsigned short*)(ws + (4u  << 20));   // 4 MB  f16
    unsigned short* hid = (unsigned short*)(ws + (8u  << 20));   // 4 MB  f16
    float*         accb = (float*)         (ws + (12u << 20));   // 8 MB  fp32

    prep_all<<<(BATCH * DIM / 4) / 256, 256, 0, stream>>>(W1, W2, z0, zbuf, W1T, W2T, zin);

    for (int s = 0; s < NSTEPS; ++s) {  // Kutta RK3: 3 stages x 2 GEMMs
        gemm8w<0><<<256, 512, 0, stream>>>(zin, W1T, b1, hid, nullptr, nullptr, nullptr);
        gemm8w<1><<<256, 512, 0, stream>>>(hid, W2T, b2, nullptr, zbuf, accb, zin);
        gemm8w<0><<<256, 512, 0, stream>>>(zin, W1T, b1, hid, nullptr, nullptr, nullptr);
        gemm8w<2><<<256, 512, 0, stream>>>(hid, W2T, b2, nullptr, zbuf, accb, zin);
        gemm8w<0><<<256, 512, 0, stream>>>(zin, W1T, b1, hid, nullptr, nullptr, nullptr);
        if (s == NSTEPS - 1)
            gemm8w<4><<<256, 512, 0, stream>>>(hid, W2T, b2, nullptr, zbuf, accb, zin);
        else
            gemm8w<3><<<256, 512, 0, stream>>>(hid, W2T, b2, nullptr, zbuf, accb, zin);
    }
}

// Round 11
// 148.750 us; speedup vs baseline: 1.4261x; 1.0684x over previous
//
#include <hip/hip_runtime.h>
#include <hip/hip_bf16.h>
#include <cstdint>
#include <cstddef>

#define BATCH   2048
#define DIM     1024   // D == H == 1024
#define NSTEPS  2      // RK3 steps; h = 1/NSTEPS

typedef __attribute__((ext_vector_type(8))) short short8;
typedef __attribute__((ext_vector_type(4))) float f32x4;
typedef _Float16 half8 __attribute__((ext_vector_type(8)));

static __device__ __forceinline__ unsigned short f2h(float x) {
    _Float16 h = (_Float16)x;                    // v_cvt_f16_f32 (RTN)
    return __builtin_bit_cast(unsigned short, h);
}

// ---------------------------------------------------------------------------
// Fused prep (ONE dispatch): z/zin init (all 2048 blocks) + W1/W2 transpose
// to f16 [N][K] (blocks 0..511, one 64x64 tile each).
// ---------------------------------------------------------------------------
__global__ __launch_bounds__(256) void prep_all(const float* __restrict__ W1,
                                                const float* __restrict__ W2,
                                                const float* __restrict__ z0,
                                                float* __restrict__ z,
                                                unsigned short* __restrict__ W1T,
                                                unsigned short* __restrict__ W2T,
                                                unsigned short* __restrict__ zin) {
    __shared__ unsigned short tile[64][65];
    const int b = blockIdx.x;

    {   // init: one float4 per thread
        const int i = b * 256 + threadIdx.x;
        float4 v = ((const float4*)z0)[i];
        ((float4*)z)[i] = v;
        ushort4 q;
        q.x = f2h(v.x); q.y = f2h(v.y); q.z = f2h(v.z); q.w = f2h(v.w);
        ((ushort4*)zin)[i] = q;
    }

    if (b < 512) {  // transpose one 64x64 tile of W1 (b<256) or W2
        const float* in = (b < 256) ? W1 : W2;
        unsigned short* out = (b < 256) ? W1T : W2T;
        const int tb = b & 255;
        const int nb = (tb & 15) * 64, kb = (tb >> 4) * 64;
        const int cx = threadIdx.x & 63, ry = threadIdx.x >> 6;
#pragma unroll
        for (int r = 0; r < 16; ++r) {
            int k = r * 4 + ry;
            tile[cx][k] = f2h(in[(size_t)(kb + k) * DIM + (nb + cx)]);
        }
        __syncthreads();
#pragma unroll
        for (int r = 0; r < 16; ++r) {
            int n = r * 4 + ry;
            out[(size_t)(nb + n) * DIM + (kb + cx)] = tile[n][cx];
        }
    }
}

// ---------------------------------------------------------------------------
// GEMM: C[m][n] = sum_k A[m][k] * Bw[n][k]  (+ fused epilogue), f16 inputs.
//
// Tile 64x64, 4 waves (256 thr), wave (rsub, wc) owns a FULL-K 32x32 output
// (2x2 frags of mfma_f32_16x16x32_f16) -> no partial-K reduce, tiny exchange.
// Grid = 512 blocks -> 2 blocks/CU (48 KB LDS): the co-resident block's main
// loop hides this block's barriers, staging latency, and epilogue (the R9 PMC
// showed ~80% stall at 1 block/CU).
// Triple-buffered staging (3 x 16 KB), counted vmcnt(4) distance-2 pipeline.
// XCD swizzle: XCD owns bm-band of 4 x all bn (512 % 8 == 0, bijective).
//
// Epilogue: waves write 32x32 f32 tiles to an 18 KB padded exchange
// (row stride 36 f32 -> 16B-aligned b128, start banks spread), then all 256
// threads own one row x 16 contiguous cols: vectorized f32x4/short8 global IO.
//
// MODE 0: hid = f16(tanh(C+b))
// MODE 1 (k1): accb = k;           zin = f16(z + (h/2) k)
// MODE 2 (k2): a0 = accb;          zin = f16(z + h (2k - a0)); accb = a0 + 4k
// MODE 3 (k3): z += (h/6)(accb+k); zin = f16(z)
// MODE 4     : like 3 but final step - no zin store
// ---------------------------------------------------------------------------
template<int MODE>
__global__ __launch_bounds__(256, 2) void gemm4w(const unsigned short* __restrict__ A,
                                                 const unsigned short* __restrict__ Bw,
                                                 const float* __restrict__ bias,
                                                 unsigned short* __restrict__ hidOut,
                                                 float* __restrict__ zbuf,
                                                 float* __restrict__ accb,
                                                 unsigned short* __restrict__ zinOut) {
    constexpr float hstep = 1.0f / NSTEPS;
    __shared__ char smem_raw[49152];             // 48 KB (staging ∪ exchange)
    short8* stg = (short8*)smem_raw;             // 3 bufs x 1024 slots (A 512 | B 512)
    float*  xch = (float*)smem_raw;              // 4 regions x 1152 f32 = 18 KB

    const int tid  = threadIdx.x;
    const int wave = tid >> 6;
    const int lane = tid & 63;
    const int l15 = lane & 15, lhi = lane >> 4;
    const int rsub = wave >> 1;        // row half of 64 (32 rows)
    const int wc   = wave & 1;         // col half of 64 (32 cols)

    // XCD swizzle: bid%8 = XCD; XCD owns bm in [xcd*4,+4) x all bn.
    const int bid = blockIdx.x;
    const int xcd = bid & 7, loc = bid >> 3;     // loc 0..63
    const int bm = xcd * 4 + (loc >> 4);         // 0..31 (2048/64)
    const int bn = loc & 15;                     // 0..15 (1024/64)

    f32x4 acc[2][2] = {};

    // Staging: 4 global_load_lds per thread (2 A + 2 B) cover 1024 slots.
    // LDS slot s (linear dest) holds global (row = s>>3, k16 = (s&7)^(row&7)).
    int offA[2], offB[2];
#pragma unroll
    for (int c = 0; c < 2; ++c) {
        const int s = c * 256 + tid;             // [0,512)
        const int row = s >> 3, k16 = (s & 7) ^ (row & 7);
        offA[c] = (bm * 64 + row) * DIM + k16 * 8;
        offB[c] = (bn * 64 + row) * DIM + k16 * 8;
    }

    auto stage = [&](int sbuf, int t) {
#pragma unroll
        for (int c = 0; c < 2; ++c)
            __builtin_amdgcn_global_load_lds(
                (const __attribute__((address_space(1))) void*)(A + offA[c] + t * 64),
                (__attribute__((address_space(3))) void*)&stg[sbuf * 1024 + c * 256 + tid],
                16, 0, 0);
#pragma unroll
        for (int c = 0; c < 2; ++c)
            __builtin_amdgcn_global_load_lds(
                (const __attribute__((address_space(1))) void*)(Bw + offB[c] + t * 64),
                (__attribute__((address_space(3))) void*)&stg[sbuf * 1024 + 512 + c * 256 + tid],
                16, 0, 0);
    };

    stage(0, 0);
    stage(1, 1);  // 8 loads in flight

    for (int t = 0; t < 16; ++t) {
        // wait for stage(t)'s 4 loads; keep the newest 4 (stage t+1) in flight
        if (t < 15) asm volatile("s_waitcnt vmcnt(4)" ::: "memory");
        else        asm volatile("s_waitcnt vmcnt(0)" ::: "memory");
        __builtin_amdgcn_s_barrier();          // raw: no vmcnt(0) drain
        __builtin_amdgcn_sched_barrier(0);     // don't hoist stage above barrier

        if (t + 2 < 16) stage((t + 2) % 3, t + 2);

        const char* sa = (const char*)&stg[(t % 3) * 1024];
        const char* sb = sa + 8192;
#pragma unroll
        for (int kk = 0; kk < 2; ++kk) {
            half8 af[2], bq[2];
#pragma unroll
            for (int m = 0; m < 2; ++m) {
                const int row  = rsub * 32 + m * 16 + l15;
                const int byte = row * 128 + ((kk * 64 + lhi * 16) ^ ((row & 7) << 4));
                af[m] = *(const half8*)(sa + byte);
            }
#pragma unroll
            for (int n = 0; n < 2; ++n) {
                const int row  = wc * 32 + n * 16 + l15;
                const int byte = row * 128 + ((kk * 64 + lhi * 16) ^ ((row & 7) << 4));
                bq[n] = *(const half8*)(sb + byte);
            }
            __builtin_amdgcn_s_setprio(1);
#pragma unroll
            for (int m = 0; m < 2; ++m)
#pragma unroll
                for (int n = 0; n < 2; ++n)
                    acc[m][n] = __builtin_amdgcn_mfma_f32_16x16x32_f16(af[m], bq[n], acc[m][n], 0, 0, 0);
            __builtin_amdgcn_s_setprio(0);
        }
    }

    __syncthreads();  // staging LDS quiesced before exchange overwrites it

    // ---- waves write full-K 32x32 tiles to the padded exchange ----
    {
        const int rbase = (rsub * 2 + wc) * 1152;   // region: 32 rows x 36 f32
#pragma unroll
        for (int m = 0; m < 2; ++m)
#pragma unroll
            for (int n = 0; n < 2; ++n)
#pragma unroll
                for (int r = 0; r < 4; ++r)
                    xch[rbase + (m * 16 + lhi * 4 + r) * 36 + n * 16 + l15] = acc[m][n][r];
    }
    __syncthreads();

    // ---- all 256 threads: one row x 16 contiguous cols each (no reduce) ----
    {
        const int row  = tid >> 2;                 // 0..63
        const int c0   = (tid & 3) << 4;           // 0,16,32,48
        const int reg  = ((row >> 5) << 1) + (c0 >> 5);
        const int base = reg * 1152 + (row & 31) * 36 + (c0 & 31);

        f32x4 sum[4];
#pragma unroll
        for (int q = 0; q < 4; ++q)
            sum[q] = *(const f32x4*)(xch + base + 4 * q);

        const int grow = bm * 64 + row;
        const int gcol = bn * 64 + c0;
        const size_t gidx = (size_t)grow * DIM + gcol;

        unsigned short hh[16];
#pragma unroll
        for (int q = 0; q < 4; ++q) {
            f32x4 v = sum[q] + *(const f32x4*)&bias[gcol + 4 * q];
            if (MODE == 0) {
#pragma unroll
                for (int j = 0; j < 4; ++j) hh[q * 4 + j] = f2h(tanhf(v[j]));
            } else if (MODE == 1) {        // k1
                *(f32x4*)&accb[gidx + 4 * q] = v;
                f32x4 z = *(const f32x4*)&zbuf[gidx + 4 * q];
#pragma unroll
                for (int j = 0; j < 4; ++j) hh[q * 4 + j] = f2h(z[j] + (0.5f * hstep) * v[j]);
            } else if (MODE == 2) {        // k2
                f32x4 a0 = *(const f32x4*)&accb[gidx + 4 * q];     // = k1
                f32x4 z  = *(const f32x4*)&zbuf[gidx + 4 * q];
#pragma unroll
                for (int j = 0; j < 4; ++j)
                    hh[q * 4 + j] = f2h(z[j] + hstep * (2.0f * v[j] - a0[j]));
                a0 += 4.0f * v;
                *(f32x4*)&accb[gidx + 4 * q] = a0;                 // k1 + 4 k2
            } else {                       // MODE 3/4: k3, finalize step
                f32x4 a0 = *(const f32x4*)&accb[gidx + 4 * q];
                f32x4 z  = *(const f32x4*)&zbuf[gidx + 4 * q];
                f32x4 zn;
#pragma unroll
                for (int j = 0; j < 4; ++j) zn[j] = z[j] + (hstep / 6.0f) * (a0[j] + v[j]);
                *(f32x4*)&zbuf[gidx + 4 * q] = zn;
                if (MODE == 3) {
#pragma unroll
                    for (int j = 0; j < 4; ++j) hh[q * 4 + j] = f2h(zn[j]);
                }
            }
        }
        if (MODE != 4) {
            short8 s0, s1;
#pragma unroll
            for (int j = 0; j < 8; ++j) { s0[j] = (short)hh[j]; s1[j] = (short)hh[j + 8]; }
            if (MODE == 0) {
                *(short8*)&hidOut[gidx] = s0;  *(short8*)&hidOut[gidx + 8] = s1;
            } else {
                *(short8*)&zinOut[gidx] = s0;  *(short8*)&zinOut[gidx + 8] = s1;
            }
        }
    }
}

// ---------------------------------------------------------------------------
extern "C" void kernel_launch(void* const* d_in, const int* in_sizes, int n_in,
                              void* d_out, int out_size, void* d_ws, size_t ws_size,
                              hipStream_t stream) {
    (void)in_sizes; (void)n_in; (void)out_size; (void)ws_size;
    const float* z0 = (const float*)d_in[0];
    const float* W1 = (const float*)d_in[1];
    const float* b1 = (const float*)d_in[2];
    const float* W2 = (const float*)d_in[3];
    const float* b2 = (const float*)d_in[4];
    float* zbuf = (float*)d_out;  // fp32 state lives in d_out

    char* ws = (char*)d_ws;
    unsigned short* W1T = (unsigned short*)(ws);                 // 2 MB  f16 [H][D]
    unsigned short* W2T = (unsigned short*)(ws + (2u  << 20));   // 2 MB  f16 [D][H]
    unsigned short* zin = (unsigned short*)(ws + (4u  << 20));   // 4 MB  f16
    unsigned short* hid = (unsigned short*)(ws + (8u  << 20));   // 4 MB  f16
    float*         accb = (float*)         (ws + (12u << 20));   // 8 MB  fp32

    prep_all<<<(BATCH * DIM / 4) / 256, 256, 0, stream>>>(W1, W2, z0, zbuf, W1T, W2T, zin);

    for (int s = 0; s < NSTEPS; ++s) {  // Kutta RK3: 3 stages x 2 GEMMs
        gemm4w<0><<<512, 256, 0, stream>>>(zin, W1T, b1, hid, nullptr, nullptr, nullptr);
        gemm4w<1><<<512, 256, 0, stream>>>(hid, W2T, b2, nullptr, zbuf, accb, zin);
        gemm4w<0><<<512, 256, 0, stream>>>(zin, W1T, b1, hid, nullptr, nullptr, nullptr);
        gemm4w<2><<<512, 256, 0, stream>>>(hid, W2T, b2, nullptr, zbuf, accb, zin);
        gemm4w<0><<<512, 256, 0, stream>>>(zin, W1T, b1, hid, nullptr, nullptr, nullptr);
        if (s == NSTEPS - 1)
            gemm4w<4><<<512, 256, 0, stream>>>(hid, W2T, b2, nullptr, zbuf, accb, zin);
        else
            gemm4w<3><<<512, 256, 0, stream>>>(hid, W2T, b2, nullptr, zbuf, accb, zin);
    }
}

// Round 12
// 130.737 us; speedup vs baseline: 1.6226x; 1.1378x over previous
//
#include <hip/hip_runtime.h>
#include <hip/hip_bf16.h>
#include <cstdint>
#include <cstddef>

#define BATCH   2048
#define DIM     1024   // D == H == 1024
#define NSTEPS  2      // RK3 steps; h = 1/NSTEPS

typedef __attribute__((ext_vector_type(8))) short short8;
typedef __attribute__((ext_vector_type(4))) float f32x4;
typedef _Float16 half8 __attribute__((ext_vector_type(8)));

static __device__ __forceinline__ unsigned short f2h(float x) {
    _Float16 h = (_Float16)x;                    // v_cvt_f16_f32 (RTN)
    return __builtin_bit_cast(unsigned short, h);
}
static __device__ __forceinline__ float h2f(unsigned short u) {
    return (float)__builtin_bit_cast(_Float16, u);
}
static __device__ __forceinline__ float tanh_fast(float x) {
    // exact at saturation (e=inf -> 1, e=0 -> -1); rel err ~2e-6
    float e = __expf(2.0f * x);
    return 1.0f - 2.0f / (e + 1.0f);
}

// ---------------------------------------------------------------------------
// Fused prep (ONE dispatch): z/zin init (all 2048 blocks) + W1/W2 transpose
// to f16 [N][K] (blocks 0..511, one 64x64 tile each).
// ---------------------------------------------------------------------------
__global__ __launch_bounds__(256) void prep_all(const float* __restrict__ W1,
                                                const float* __restrict__ W2,
                                                const float* __restrict__ z0,
                                                float* __restrict__ z,
                                                unsigned short* __restrict__ W1T,
                                                unsigned short* __restrict__ W2T,
                                                unsigned short* __restrict__ zin) {
    __shared__ unsigned short tile[64][65];
    const int b = blockIdx.x;

    {   // init: one float4 per thread
        const int i = b * 256 + threadIdx.x;
        float4 v = ((const float4*)z0)[i];
        ((float4*)z)[i] = v;
        ushort4 q;
        q.x = f2h(v.x); q.y = f2h(v.y); q.z = f2h(v.z); q.w = f2h(v.w);
        ((ushort4*)zin)[i] = q;
    }

    if (b < 512) {  // transpose one 64x64 tile of W1 (b<256) or W2
        const float* in = (b < 256) ? W1 : W2;
        unsigned short* out = (b < 256) ? W1T : W2T;
        const int tb = b & 255;
        const int nb = (tb & 15) * 64, kb = (tb >> 4) * 64;
        const int cx = threadIdx.x & 63, ry = threadIdx.x >> 6;
#pragma unroll
        for (int r = 0; r < 16; ++r) {
            int k = r * 4 + ry;
            tile[cx][k] = f2h(in[(size_t)(kb + k) * DIM + (nb + cx)]);
        }
        __syncthreads();
#pragma unroll
        for (int r = 0; r < 16; ++r) {
            int n = r * 4 + ry;
            out[(size_t)(nb + n) * DIM + (kb + cx)] = tile[n][cx];
        }
    }
}

// ---------------------------------------------------------------------------
// GEMM: C[m][n] = sum_k A[m][k] * Bw[n][k]  (+ fused epilogue), f16 inputs.
//
// Tile 64x64, 4 waves, wave (rsub,wc) owns a full-K 32x32 output (2x2 frags
// of mfma_f32_16x16x32_f16). Grid 512 -> 2 blocks/CU (48 KB LDS) for TLP.
// Triple-buffered staging, counted vmcnt(4) distance-2 pipeline, FULLY
// UNROLLED 16-step K-loop (compile-time buffer indices / LDS bases).
// Both kk sub-steps' ds_reads batched before one 8-MFMA setprio cluster.
// XCD swizzle: XCD owns bm-band of 4 x all bn.
//
// Epilogue: padded 18 KB exchange (stride 36 f32), then 256 threads own one
// row x 16 contiguous cols; vectorized f32x4/short8 global IO. accb is f16.
//
// MODE 0: hid = f16(tanh(C+b))
// MODE 1 (k1): accb = f16(k);      zin = f16(z + (h/2) k)
// MODE 2 (k2): a0 = accb;          zin = f16(z + h (2k - a0)); accb = f16(a0 + 4k)
// MODE 3 (k3): z += (h/6)(accb+k); zin = f16(z)
// MODE 4     : like 3 but final step - no zin store
// ---------------------------------------------------------------------------
template<int MODE>
__global__ __launch_bounds__(256, 2) void gemm4w(const unsigned short* __restrict__ A,
                                                 const unsigned short* __restrict__ Bw,
                                                 const float* __restrict__ bias,
                                                 unsigned short* __restrict__ hidOut,
                                                 float* __restrict__ zbuf,
                                                 unsigned short* __restrict__ accb,
                                                 unsigned short* __restrict__ zinOut) {
    constexpr float hstep = 1.0f / NSTEPS;
    __shared__ char smem_raw[49152];             // 48 KB (staging ∪ exchange)
    short8* stg = (short8*)smem_raw;             // 3 bufs x 1024 slots (A 512 | B 512)
    float*  xch = (float*)smem_raw;              // 4 regions x 1152 f32 = 18 KB

    const int tid  = threadIdx.x;
    const int wave = tid >> 6;
    const int lane = tid & 63;
    const int l15 = lane & 15, lhi = lane >> 4;
    const int rsub = wave >> 1;        // row half of 64
    const int wc   = wave & 1;         // col half of 64

    // XCD swizzle: bid%8 = XCD; XCD owns bm in [xcd*4,+4) x all bn.
    const int bid = blockIdx.x;
    const int xcd = bid & 7, loc = bid >> 3;     // loc 0..63
    const int bm = xcd * 4 + (loc >> 4);         // 0..31
    const int bn = loc & 15;                     // 0..15

    f32x4 acc[2][2] = {};

    // Staging: 4 global_load_lds per thread (2 A + 2 B) cover 1024 slots.
    // LDS slot s (linear dest) holds global (row = s>>3, k16 = (s&7)^(row&7)).
    int offA[2], offB[2];
#pragma unroll
    for (int c = 0; c < 2; ++c) {
        const int s = c * 256 + tid;             // [0,512)
        const int row = s >> 3, k16 = (s & 7) ^ (row & 7);
        offA[c] = (bm * 64 + row) * DIM + k16 * 8;
        offB[c] = (bn * 64 + row) * DIM + k16 * 8;
    }

    auto stage = [&](int sbuf, int t) {
#pragma unroll
        for (int c = 0; c < 2; ++c)
            __builtin_amdgcn_global_load_lds(
                (const __attribute__((address_space(1))) void*)(A + offA[c] + t * 64),
                (__attribute__((address_space(3))) void*)&stg[sbuf * 1024 + c * 256 + tid],
                16, 0, 0);
#pragma unroll
        for (int c = 0; c < 2; ++c)
            __builtin_amdgcn_global_load_lds(
                (const __attribute__((address_space(1))) void*)(Bw + offB[c] + t * 64),
                (__attribute__((address_space(3))) void*)&stg[sbuf * 1024 + 512 + c * 256 + tid],
                16, 0, 0);
    };

    stage(0, 0);
    stage(1, 1);  // 8 loads in flight

    // Pre-computed per-lane swizzled LDS byte offsets (row-invariant parts).
    const int arow0 = rsub * 32 + l15;           // +16 for m=1
    const int brow0 = wc   * 32 + l15;           // +16 for n=1

#pragma unroll
    for (int t = 0; t < 16; ++t) {
        if (t < 15) asm volatile("s_waitcnt vmcnt(4)" ::: "memory");
        else        asm volatile("s_waitcnt vmcnt(0)" ::: "memory");
        __builtin_amdgcn_s_barrier();          // raw: no vmcnt(0) drain
        __builtin_amdgcn_sched_barrier(0);     // don't hoist stage above barrier

        if (t + 2 < 16) stage((t + 2) % 3, t + 2);

        const char* sa = (const char*)&stg[(t % 3) * 1024];
        const char* sb = sa + 8192;
        half8 af[2][2], bq[2][2];
#pragma unroll
        for (int kk = 0; kk < 2; ++kk) {
#pragma unroll
            for (int m = 0; m < 2; ++m) {
                const int row  = arow0 + m * 16;
                const int byte = row * 128 + ((kk * 64 + lhi * 16) ^ ((row & 7) << 4));
                af[kk][m] = *(const half8*)(sa + byte);
            }
#pragma unroll
            for (int n = 0; n < 2; ++n) {
                const int row  = brow0 + n * 16;
                const int byte = row * 128 + ((kk * 64 + lhi * 16) ^ ((row & 7) << 4));
                bq[kk][n] = *(const half8*)(sb + byte);
            }
        }
        __builtin_amdgcn_s_setprio(1);
#pragma unroll
        for (int kk = 0; kk < 2; ++kk)
#pragma unroll
            for (int m = 0; m < 2; ++m)
#pragma unroll
                for (int n = 0; n < 2; ++n)
                    acc[m][n] = __builtin_amdgcn_mfma_f32_16x16x32_f16(af[kk][m], bq[kk][n], acc[m][n], 0, 0, 0);
        __builtin_amdgcn_s_setprio(0);
    }

    __syncthreads();  // staging LDS quiesced before exchange overwrites it

    // ---- waves write full-K 32x32 tiles to the padded exchange ----
    {
        const int rbase = (rsub * 2 + wc) * 1152;   // region: 32 rows x 36 f32
#pragma unroll
        for (int m = 0; m < 2; ++m)
#pragma unroll
            for (int n = 0; n < 2; ++n)
#pragma unroll
                for (int r = 0; r < 4; ++r)
                    xch[rbase + (m * 16 + lhi * 4 + r) * 36 + n * 16 + l15] = acc[m][n][r];
    }
    __syncthreads();

    // ---- all 256 threads: one row x 16 contiguous cols each ----
    {
        const int row  = tid >> 2;                 // 0..63
        const int c0   = (tid & 3) << 4;           // 0,16,32,48
        const int reg  = ((row >> 5) << 1) + (c0 >> 5);
        const int base = reg * 1152 + (row & 31) * 36 + (c0 & 31);

        f32x4 sum[4];
#pragma unroll
        for (int q = 0; q < 4; ++q)
            sum[q] = *(const f32x4*)(xch + base + 4 * q);

        const int grow = bm * 64 + row;
        const int gcol = bn * 64 + c0;
        const size_t gidx = (size_t)grow * DIM + gcol;

        // f16 accb fragment (16 halves) for modes 2/3/4
        unsigned short al[16];
        if (MODE >= 2) {
            short8 a0 = *(const short8*)&accb[gidx];
            short8 a1 = *(const short8*)&accb[gidx + 8];
#pragma unroll
            for (int j = 0; j < 8; ++j) {
                al[j]     = (unsigned short)a0[j];
                al[j + 8] = (unsigned short)a1[j];
            }
        }

        unsigned short hh[16];
        unsigned short na[16];   // new accb (modes 1,2)
#pragma unroll
        for (int q = 0; q < 4; ++q) {
            f32x4 v = sum[q] + *(const f32x4*)&bias[gcol + 4 * q];
            if (MODE == 0) {
#pragma unroll
                for (int j = 0; j < 4; ++j) hh[q * 4 + j] = f2h(tanh_fast(v[j]));
            } else if (MODE == 1) {        // k1
                f32x4 z = *(const f32x4*)&zbuf[gidx + 4 * q];
#pragma unroll
                for (int j = 0; j < 4; ++j) {
                    na[q * 4 + j] = f2h(v[j]);
                    hh[q * 4 + j] = f2h(z[j] + (0.5f * hstep) * v[j]);
                }
            } else if (MODE == 2) {        // k2
                f32x4 z = *(const f32x4*)&zbuf[gidx + 4 * q];
#pragma unroll
                for (int j = 0; j < 4; ++j) {
                    const float k1 = h2f(al[q * 4 + j]);
                    hh[q * 4 + j] = f2h(z[j] + hstep * (2.0f * v[j] - k1));
                    na[q * 4 + j] = f2h(k1 + 4.0f * v[j]);
                }
            } else {                       // MODE 3/4: k3, finalize step
                f32x4 z = *(const f32x4*)&zbuf[gidx + 4 * q];
                f32x4 zn;
#pragma unroll
                for (int j = 0; j < 4; ++j)
                    zn[j] = z[j] + (hstep / 6.0f) * (h2f(al[q * 4 + j]) + v[j]);
                *(f32x4*)&zbuf[gidx + 4 * q] = zn;
                if (MODE == 3) {
#pragma unroll
                    for (int j = 0; j < 4; ++j) hh[q * 4 + j] = f2h(zn[j]);
                }
            }
        }
        if (MODE != 4) {
            short8 s0, s1;
#pragma unroll
            for (int j = 0; j < 8; ++j) { s0[j] = (short)hh[j]; s1[j] = (short)hh[j + 8]; }
            if (MODE == 0) {
                *(short8*)&hidOut[gidx] = s0;  *(short8*)&hidOut[gidx + 8] = s1;
            } else {
                *(short8*)&zinOut[gidx] = s0;  *(short8*)&zinOut[gidx + 8] = s1;
            }
        }
        if (MODE == 1 || MODE == 2) {
            short8 a0, a1;
#pragma unroll
            for (int j = 0; j < 8; ++j) { a0[j] = (short)na[j]; a1[j] = (short)na[j + 8]; }
            *(short8*)&accb[gidx] = a0;  *(short8*)&accb[gidx + 8] = a1;
        }
    }
}

// ---------------------------------------------------------------------------
extern "C" void kernel_launch(void* const* d_in, const int* in_sizes, int n_in,
                              void* d_out, int out_size, void* d_ws, size_t ws_size,
                              hipStream_t stream) {
    (void)in_sizes; (void)n_in; (void)out_size; (void)ws_size;
    const float* z0 = (const float*)d_in[0];
    const float* W1 = (const float*)d_in[1];
    const float* b1 = (const float*)d_in[2];
    const float* W2 = (const float*)d_in[3];
    const float* b2 = (const float*)d_in[4];
    float* zbuf = (float*)d_out;  // fp32 state lives in d_out

    char* ws = (char*)d_ws;
    unsigned short* W1T = (unsigned short*)(ws);                 // 2 MB  f16 [H][D]
    unsigned short* W2T = (unsigned short*)(ws + (2u  << 20));   // 2 MB  f16 [D][H]
    unsigned short* zin = (unsigned short*)(ws + (4u  << 20));   // 4 MB  f16
    unsigned short* hid = (unsigned short*)(ws + (8u  << 20));   // 4 MB  f16
    unsigned short* accb= (unsigned short*)(ws + (12u << 20));   // 4 MB  f16

    prep_all<<<(BATCH * DIM / 4) / 256, 256, 0, stream>>>(W1, W2, z0, zbuf, W1T, W2T, zin);

    for (int s = 0; s < NSTEPS; ++s) {  // Kutta RK3: 3 stages x 2 GEMMs
        gemm4w<0><<<512, 256, 0, stream>>>(zin, W1T, b1, hid, nullptr, nullptr, nullptr);
        gemm4w<1><<<512, 256, 0, stream>>>(hid, W2T, b2, nullptr, zbuf, accb, zin);
        gemm4w<0><<<512, 256, 0, stream>>>(zin, W1T, b1, hid, nullptr, nullptr, nullptr);
        gemm4w<2><<<512, 256, 0, stream>>>(hid, W2T, b2, nullptr, zbuf, accb, zin);
        gemm4w<0><<<512, 256, 0, stream>>>(zin, W1T, b1, hid, nullptr, nullptr, nullptr);
        if (s == NSTEPS - 1)
            gemm4w<4><<<512, 256, 0, stream>>>(hid, W2T, b2, nullptr, zbuf, accb, zin);
        else
            gemm4w<3><<<512, 256, 0, stream>>>(hid, W2T, b2, nullptr, zbuf, accb, zin);
    }
}